// Round 9
// baseline (271.325 us; speedup 1.0000x reference)
//
#include <hip/hip_runtime.h>
#include <hip/hip_bf16.h>

#define NN 50000      // nodes
#define NE 800000     // edges
#define NR 500        // relations
#define KEH 256       // input feat dim
#define KRH 128       // proj feat dim
#define NSB 8         // node super-bins (node / 6250), aligned to 8 XCDs
#define SBW 6250      // super-bin width
#define NBK (NR*NSB)  // 4000 buckets
#define NBE 256       // edge-pass blocks (k_edge / k_mkrec)
#define EPB (NE/NBE)  // 3125 edges per block
#define NTILE 3125    // 16-row GEMM tiles (50000/16 exactly)

typedef __attribute__((ext_vector_type(8))) __bf16 bf16x8;
typedef __attribute__((ext_vector_type(4))) float f32x4;

// ---- workspace layout (bytes, 16B aligned), total ~63.4 MiB ----
#define OFF_XH     0UL            // [NN][128] bf16
#define OFF_XT     12800000UL     // [NN][128] bf16
#define OFF_SP     25600000UL     // [NN] float4
#define OFF_DP     26400000UL     // [NN] float4
#define OFF_SUMS   27200000UL     // [NR*4] f32 (8000 B)
#define OFF_HISTH  27208000UL     // [NBK] u32 totals (16000 B)
#define OFF_HISTT  27224000UL     // [NBK] u32 totals (16000 B)
// zero region SUMS..HISTT = 40000 B = 10000 u32
#define OFF_INVS   27240000UL     // [NR*4] f32
#define OFF_BASEH  27248000UL     // [NBK+1] u32 (16016 B)
#define OFF_BASET  27264016UL     // [NBK+1] u32
#define OFF_RECH   27312032UL     // [NE] uint2 (node, w1) 6.4 MB
#define OFF_RECT   33712032UL     // [NE] uint2 (node, w2) 6.4 MB
#define OFF_PART   40112032UL     // [NBK][128] f32 partials (2.048 MB)
#define OFF_AH     42160032UL     // [256] f32
#define OFF_AT     42161056UL     // [256] f32
#define OFF_FLAG   42162080UL     // u32
#define OFF_WHH    42162144UL     // [128][256] bf16, FRAGMENT order
#define OFF_WHL    42227680UL     // (unused since compensation dropped)
#define OFF_WTH    42293216UL
#define OFF_WTL    42358752UL     // (unused)
#define OFF_CURSH  42424288UL     // [NBK] u32 atomic scatter cursors (16 KB)
#define OFF_CURST  42440288UL     // [NBK] u32
#define OFF_EX     50616288UL     // [NE] float4 exp-scores 12.8 MB
// end 63,416,288

__device__ __forceinline__ int clampi(int v, int hi) {  // [0, hi)
    v = v < 0 ? 0 : v;
    return v >= hi ? hi - 1 : v;
}

// Wave-replicated dtype sniff (see round-8 notes).
__device__ __forceinline__ int sniff_isbf(const unsigned* xe_raw) {
    int lane = threadIdx.x & 63;
    unsigned w = xe_raw[lane];
    unsigned ex = (w >> 7) & 0xFFu;
    bool hit = (ex >= 115u && ex <= 131u);
    return __popcll(__ballot(hit)) >= 32;
}

// block 0: flag + a_h/a_t convert. blocks 1..128: weight -> FRAGMENT order
// (bf16 cast, no error-compensation split). blocks 129+: zero sums + histH +
// histT (10000 u32).
// Frag order: out index o = ((ct*8+ks)*64 + q*16 + c)*8 + e  holds
// w[ct*16+c][ks*32+q*8+e]  — so lane l=q*16+c of fragment (ct,ks) reads its
// 8 contiguous bf16 (col=l&15, k-seg=(l>>4)*8) as one 16B chunk, and the
// LDS stage is a linear 64KB copy.
__global__ __launch_bounds__(256) void k_init(const unsigned* __restrict__ xe_raw,
                                              const void* __restrict__ ah_in, const void* __restrict__ at_in,
                                              const void* __restrict__ wh, const void* __restrict__ wt,
                                              unsigned* __restrict__ flag, float* __restrict__ ah32,
                                              float* __restrict__ at32,
                                              __bf16* __restrict__ whh, __bf16* __restrict__ wth,
                                              unsigned* __restrict__ zero1) {
    int isbf = sniff_isbf(xe_raw);
    int t = threadIdx.x;
    if (blockIdx.x == 0) {
        if (t == 0) flag[0] = (unsigned)isbf;
        ah32[t] = isbf ? __bfloat162float(((const __hip_bfloat16*)ah_in)[t]) : ((const float*)ah_in)[t];
        at32[t] = isbf ? __bfloat162float(((const __hip_bfloat16*)at_in)[t]) : ((const float*)at_in)[t];
    } else if (blockIdx.x <= 128) {
        int o = (blockIdx.x - 1) * 256 + t;   // [0, 32768) frag-order output idx
        int e = o & 7, c = (o >> 3) & 15, q = (o >> 7) & 3, ks = (o >> 9) & 7, ct = o >> 12;
        int i = (ct * 16 + c) * KEH + ks * 32 + q * 8 + e;   // row-major source
        if (isbf) {
            whh[o] = ((const __bf16*)wh)[i];
            wth[o] = ((const __bf16*)wt)[i];
        } else {
            whh[o] = (__bf16)((const float*)wh)[i];
            wth[o] = (__bf16)((const float*)wt)[i];
        }
    } else {
        int stride = (gridDim.x - 129) * 256;
        for (int i = (blockIdx.x - 129) * 256 + t; i < 10000; i += stride) zero1[i] = 0u;
    }
}

// Split-phase GEMM + fused per-node scores, single-term bf16 MFMA.
// Grid 512 x 512 thr (8 waves; 64KB LDS -> 2 blocks/CU resident).
// phase = bid&1 (0=H->xh, 1=T->xt). Block stages its phase's weight matrix
// (64 KB, linear copy — k_init wrote fragment order) into LDS once; waves
// grid-stride over 16-row tiles: 8 A-frag loads (fp32: 16 float4 + bf16
// cast; rounding error ~0.3% is at the same scale as the bf16 store of
// xh/xt — measured: absmax identical to the compensated version), 64
// {ds_read_b128 + MFMA}, epilogue: xh/xt stores + 4 score dot-products/row
// via 16-lane shfl_xor, written to the phase's disjoint float2 halves of
// sp/dp.
__global__ __launch_bounds__(512, 4) void k_gemm(const void* __restrict__ xe,
                                              const unsigned* __restrict__ flag,
                                              const __bf16* __restrict__ whh, const __bf16* __restrict__ wth,
                                              const float* __restrict__ ah, const float* __restrict__ at,
                                              __hip_bfloat16* __restrict__ xh, __hip_bfloat16* __restrict__ xt,
                                              float2* __restrict__ sp2, float2* __restrict__ dp2) {
    __shared__ uint4 lb[4096];    // 64 KiB: this phase's weight matrix, frag order
    const int t = threadIdx.x, lane = t & 63, wave = t >> 6;
    const int l16 = lane & 15, quad = lane >> 4;
    const int ph = blockIdx.x & 1;
    const int isbf = (int)flag[0];
    const __bf16* wfh = ph ? wth : whh;

    {   // linear 64 KB stage: 512 thr x 8 x 16B
        const uint4* wsrc = (const uint4*)wfh;
        #pragma unroll
        for (int i = 0; i < 8; ++i) lb[i * 512 + t] = wsrc[i * 512 + t];
    }
    __syncthreads();

    __hip_bfloat16* out = ph ? xt : xh;
    for (int tile = (int)(blockIdx.x >> 1) * 8 + wave; tile < NTILE; tile += 2048) {
        const int row = tile * 16 + l16;       // this lane's A row
        bf16x8 a[8];
        if (isbf) {
            const __bf16* xb = (const __bf16*)xe + (size_t)row * KEH;
            #pragma unroll
            for (int ks = 0; ks < 8; ++ks)
                a[ks] = *(const bf16x8*)(xb + ks * 32 + quad * 8);
        } else {
            const float* xf = (const float*)xe + (size_t)row * KEH;
            #pragma unroll
            for (int ks = 0; ks < 8; ++ks) {
                const float* p = xf + ks * 32 + quad * 8;
                float4 u0 = *(const float4*)p, u1 = *(const float4*)(p + 4);
                a[ks][0] = (__bf16)u0.x; a[ks][1] = (__bf16)u0.y;
                a[ks][2] = (__bf16)u0.z; a[ks][3] = (__bf16)u0.w;
                a[ks][4] = (__bf16)u1.x; a[ks][5] = (__bf16)u1.y;
                a[ks][6] = (__bf16)u1.z; a[ks][7] = (__bf16)u1.w;
            }
        }

        f32x4 acc[8];
        #pragma unroll
        for (int ct = 0; ct < 8; ++ct) acc[ct] = (f32x4){0.f, 0.f, 0.f, 0.f};
        #pragma unroll
        for (int ks = 0; ks < 8; ++ks)
            #pragma unroll
            for (int ct = 0; ct < 8; ++ct)
                acc[ct] = __builtin_amdgcn_mfma_f32_16x16x32_bf16(
                    a[ks], *(const bf16x8*)&lb[(ct * 8 + ks) * 64 + lane], acc[ct], 0, 0, 0);

        // ---- epilogue: store projected rows + fused scores ----
        float s0[4] = {0.f,0.f,0.f,0.f}, s1[4] = {0.f,0.f,0.f,0.f};
        float s2[4] = {0.f,0.f,0.f,0.f}, s3[4] = {0.f,0.f,0.f,0.f};
        #pragma unroll
        for (int ct = 0; ct < 8; ++ct) {
            int c = ct * 16 + l16;
            float va0 = ah[c], va1 = ah[128 + c];
            float vb0 = at[c], vb1 = at[128 + c];
            #pragma unroll
            for (int jj = 0; jj < 4; ++jj) {
                float v = acc[ct][jj];
                s0[jj] = fmaf(v, va0, s0[jj]);
                s1[jj] = fmaf(v, va1, s1[jj]);
                s2[jj] = fmaf(v, vb0, s2[jj]);
                s3[jj] = fmaf(v, vb1, s3[jj]);
                out[(size_t)(tile * 16 + quad * 4 + jj) * KRH + c] = __float2bfloat16(v);
            }
        }
        #pragma unroll
        for (int off = 8; off; off >>= 1)
            #pragma unroll
            for (int jj = 0; jj < 4; ++jj) {
                s0[jj] += __shfl_xor(s0[jj], off);
                s1[jj] += __shfl_xor(s1[jj], off);
                s2[jj] += __shfl_xor(s2[jj], off);
                s3[jj] += __shfl_xor(s3[jj], off);
            }
        if (l16 == 0) {
            // sp = (s_hh0, s_hh1, s_th0, s_th1); dp = (s_tt0, s_tt1, s_ht0, s_ht1)
            #pragma unroll
            for (int jj = 0; jj < 4; ++jj) {
                int n = tile * 16 + quad * 4 + jj;
                if (ph == 0) {
                    sp2[n * 2 + 0] = make_float2(s0[jj], s1[jj]);   // s_hh
                    dp2[n * 2 + 1] = make_float2(s2[jj], s3[jj]);   // s_ht
                } else {
                    sp2[n * 2 + 1] = make_float2(s0[jj], s1[jj]);   // s_th
                    dp2[n * 2 + 0] = make_float2(s2[jj], s3[jj]);   // s_tt
                }
            }
        }
    }
}

__device__ __forceinline__ float eexp(float x) {
    x = x > 0.f ? x : 0.01f * x;
    x = fminf(x, 50.f);
    return __expf(x);
}

// Per edge (contiguous 3125-edge range per block, 1024 thr = 16 waves/CU):
// 4 exp scores -> ex4 store + LDS segment sums + (rel,sbin) histograms ->
// global totals (atomic). Per-block hpb rows dropped (round-9): scatter
// placement now uses global atomic cursors in k_mkrec, so only totals are
// needed.
__global__ __launch_bounds__(1024) void k_edge(const int* __restrict__ src, const int* __restrict__ dst,
                                               const int* __restrict__ rel,
                                               const float4* __restrict__ sp, const float4* __restrict__ dp,
                                               float* __restrict__ sums,
                                               unsigned* __restrict__ histH, unsigned* __restrict__ histT,
                                               float4* __restrict__ ex4) {
    __shared__ float ls[NR * 4];
    __shared__ unsigned lhH[NBK], lhT[NBK];
    int t = threadIdx.x;
    for (int i = t; i < NR * 4; i += 1024) ls[i] = 0.f;
    for (int i = t; i < NBK; i += 1024) { lhH[i] = 0u; lhT[i] = 0u; }
    __syncthreads();
    unsigned lo = blockIdx.x * EPB, hi = lo + EPB;
    for (unsigned e = lo + t; e < hi; e += 1024) {
        int s = clampi(src[e], NN), d = clampi(dst[e], NN), r = clampi(rel[e], NR);
        float4 a = sp[s], b = dp[d];
        float4 ex;
        ex.x = eexp(a.x + b.x); ex.y = eexp(a.y + b.y);
        ex.z = eexp(a.z + b.z); ex.w = eexp(a.w + b.w);
        ex4[e] = ex;
        atomicAdd(&ls[r*4+0], ex.x);
        atomicAdd(&ls[r*4+1], ex.y);
        atomicAdd(&ls[r*4+2], ex.z);
        atomicAdd(&ls[r*4+3], ex.w);
        atomicAdd(&lhH[r * NSB + s / SBW], 1u);
        atomicAdd(&lhT[r * NSB + d / SBW], 1u);
    }
    __syncthreads();
    for (int i = t; i < NR * 4; i += 1024)
        if (ls[i] != 0.f) atomicAdd(&sums[i], ls[i]);
    for (int i = t; i < NBK; i += 1024) {
        unsigned cH = lhH[i], cT = lhT[i];
        if (cH) atomicAdd(&histH[i], cH);
        if (cT) atomicAdd(&histT[i], cT);
    }
}

// Scan both 4000-bin total histograms -> bucket bases AND scatter cursors
// (cursX starts equal to baseX; k_mkrec bumps cursors atomically);
// invs = 1/(sums+eps).
__global__ __launch_bounds__(1024) void k_scan2(const unsigned* __restrict__ histH,
                                                const unsigned* __restrict__ histT,
                                                const float* __restrict__ sums,
                                                unsigned* __restrict__ baseH, unsigned* __restrict__ baseT,
                                                unsigned* __restrict__ cursH, unsigned* __restrict__ cursT,
                                                float* __restrict__ invs) {
    __shared__ unsigned sc[1024];
    int t = threadIdx.x;
    for (int pass = 0; pass < 2; ++pass) {
        const unsigned* h = pass ? histT : histH;
        unsigned* base = pass ? baseT : baseH;
        unsigned* curs = pass ? cursT : cursH;
        int j0 = t * 4;
        unsigned v[4], s = 0;
        for (int k = 0; k < 4; ++k) { v[k] = (j0 + k < NBK) ? h[j0 + k] : 0u; s += v[k]; }
        sc[t] = s;
        __syncthreads();
        for (int off = 1; off < 1024; off <<= 1) {
            unsigned add = (t >= off) ? sc[t - off] : 0u;
            __syncthreads();
            sc[t] += add;
            __syncthreads();
        }
        unsigned run = sc[t] - s;
        for (int k = 0; k < 4; ++k) {
            if (j0 + k < NBK) { base[j0 + k] = run; curs[j0 + k] = run; run += v[k]; }
        }
        if (t == 1023) base[NBK] = sc[1023];
        __syncthreads();
    }
    for (int i = t; i < NR * 4; i += 1024) invs[i] = 1.f / (sums[i] + 1e-16f);
}

// Single-pass scatter (1024 thr): weights from streamed ex4 (no gathers, no
// exp); placement via global atomic cursors (record order within a bucket is
// irrelevant — k_accR sums). Replaces the hpb + k_colscan machinery.
__global__ __launch_bounds__(1024) void k_mkrec(const int* __restrict__ src, const int* __restrict__ dst,
                                                const int* __restrict__ rel,
                                                const float4* __restrict__ ex4,
                                                const float4* __restrict__ invs4,
                                                unsigned* __restrict__ cursH, unsigned* __restrict__ cursT,
                                                uint2* __restrict__ recH, uint2* __restrict__ recT) {
    unsigned lo = blockIdx.x * EPB, hi = lo + EPB;
    for (unsigned e = lo + threadIdx.x; e < hi; e += 1024) {
        int s = clampi(src[e], NN), d = clampi(dst[e], NN), r = clampi(rel[e], NR);
        float4 ex = ex4[e];
        float4 iv = invs4[r];
        float w1 = ex.x * iv.x + ex.y * iv.y;
        float w2 = ex.z * iv.z + ex.w * iv.w;
        unsigned pH = atomicAdd(&cursH[r * NSB + s / SBW], 1u);
        unsigned pT = atomicAdd(&cursT[r * NSB + d / SBW], 1u);
        if (pH < NE) recH[pH] = make_uint2((unsigned)s, __float_as_uint(w1));
        if (pT < NE) recT[pT] = make_uint2((unsigned)d, __float_as_uint(w2));
    }
}

// One block per (rel,sbin) bucket. Chunked rec staging (256/LDS burst), then
// 16-lane-group gather: each wave processes 4 records/iter, 8 cols/lane via
// one b128 load — ~6 wave-instr/record vs 13 for the old 64-lane/u32 shape
// (round-7 pmc: VALUBusy 75%, MfmaUtil 0 -> VALU-issue-bound). Group reduce:
// shfl_xor(16,32) then LDS cross-wave sum.
__global__ __launch_bounds__(256) void k_accR(const uint2* __restrict__ recH, const uint2* __restrict__ recT,
                                              const unsigned* __restrict__ baseH, const unsigned* __restrict__ baseT,
                                              const __hip_bfloat16* __restrict__ xh,
                                              const __hip_bfloat16* __restrict__ xt,
                                              float* __restrict__ part) {
    __shared__ float red[3][128];
    __shared__ uint2 lrec[256];
    int b = blockIdx.x;
    int t = threadIdx.x, lane = t & 63, wv = t >> 6;
    int l16 = lane & 15, g = lane >> 4;      // col sub-slice, record subgroup
    float az[8];
    #pragma unroll
    for (int k = 0; k < 8; ++k) az[k] = 0.f;

    for (int pass = 0; pass < 2; ++pass) {
        const uint2* rec = pass ? recT : recH;
        const unsigned* base = pass ? baseT : baseH;
        const uint4* xs = (const uint4*)(pass ? xt : xh);   // row = 16 uint4
        unsigned b0 = base[b];
        unsigned cnt = base[b + 1] - b0;
        if (cnt > NE) cnt = 0;        // poison guard
        for (unsigned cb = 0; cb < cnt; cb += 256u) {
            unsigned cn = cnt - cb; if (cn > 256u) cn = 256u;
            __syncthreads();                       // prior chunk readers done
            if ((unsigned)t < cn) lrec[t] = rec[b0 + cb + t];
            __syncthreads();
            // wave wv, group g covers records j = wv*4+g, +16, ...
            for (unsigned j = (unsigned)(wv * 4 + g); j < cn; j += 16u) {
                uint2 v = lrec[j];
                unsigned nd = v.x < NN ? v.x : 0u;     // poison guard
                float w = __uint_as_float(v.y);
                uint4 u = xs[(size_t)nd * 16 + l16];
                az[0] = fmaf(w, __uint_as_float(u.x << 16),          az[0]);
                az[1] = fmaf(w, __uint_as_float(u.x & 0xffff0000u),  az[1]);
                az[2] = fmaf(w, __uint_as_float(u.y << 16),          az[2]);
                az[3] = fmaf(w, __uint_as_float(u.y & 0xffff0000u),  az[3]);
                az[4] = fmaf(w, __uint_as_float(u.z << 16),          az[4]);
                az[5] = fmaf(w, __uint_as_float(u.z & 0xffff0000u),  az[5]);
                az[6] = fmaf(w, __uint_as_float(u.w << 16),          az[6]);
                az[7] = fmaf(w, __uint_as_float(u.w & 0xffff0000u),  az[7]);
            }
        }
    }
    // reduce the 4 record-subgroups: lanes 0-15 end with column totals
    #pragma unroll
    for (int k = 0; k < 8; ++k) {
        az[k] += __shfl_xor(az[k], 16);
        az[k] += __shfl_xor(az[k], 32);
    }
    __syncthreads();                  // lrec dead; red reuse safe
    if (wv > 0 && lane < 16) {
        #pragma unroll
        for (int k = 0; k < 8; ++k) red[wv - 1][l16 * 8 + k] = az[k];
    }
    __syncthreads();
    if (wv == 0 && lane < 16) {
        #pragma unroll
        for (int k = 0; k < 8; ++k) {
            float s = az[k] + red[0][l16 * 8 + k] + red[1][l16 * 8 + k] + red[2][l16 * 8 + k];
            part[(size_t)b * KRH + l16 * 8 + k] = s;
        }
    }
}

// out[r][c] = 0.25 * sum_sbin part[r*8+sbin][c]; dtype follows input.
__global__ __launch_bounds__(256) void k_out(const float* __restrict__ part,
                                             const unsigned* __restrict__ flag, void* __restrict__ out) {
    int i = blockIdx.x * 256 + threadIdx.x;
    if (i < NR * KRH) {
        int r = i >> 7, c = i & 127;
        float v = 0.f;
        for (int s = 0; s < NSB; ++s) v += part[(size_t)(r * NSB + s) * KRH + c];
        v *= 0.25f;                   // / num_heads(2) / 2
        if (!isfinite(v)) v = 0.f;
        if (flag[0]) ((__hip_bfloat16*)out)[i] = __float2bfloat16(v);
        else         ((float*)out)[i] = v;
    }
}

extern "C" void kernel_launch(void* const* d_in, const int* in_sizes, int n_in,
                              void* d_out, int out_size, void* d_ws, size_t ws_size,
                              hipStream_t stream) {
    const void* xe  = d_in[0];
    const int* eidx = (const int*)d_in[1];
    const int* rel  = (const int*)d_in[2];
    const void* wh  = d_in[3];
    const void* wt  = d_in[4];
    const void* ahp = d_in[5];
    const void* atp = d_in[6];

    const int* src = eidx;
    const int* dst = eidx + NE;

    char* ws = (char*)d_ws;
    __hip_bfloat16* xh = (__hip_bfloat16*)(ws + OFF_XH);
    __hip_bfloat16* xt = (__hip_bfloat16*)(ws + OFF_XT);
    float4*   sp     = (float4*)(ws + OFF_SP);
    float4*   dp     = (float4*)(ws + OFF_DP);
    float*    sums   = (float*)(ws + OFF_SUMS);
    unsigned* histH  = (unsigned*)(ws + OFF_HISTH);
    unsigned* histT  = (unsigned*)(ws + OFF_HISTT);
    float*    invs   = (float*)(ws + OFF_INVS);
    unsigned* baseH  = (unsigned*)(ws + OFF_BASEH);
    unsigned* baseT  = (unsigned*)(ws + OFF_BASET);
    uint2*    recH   = (uint2*)(ws + OFF_RECH);
    uint2*    recT   = (uint2*)(ws + OFF_RECT);
    float*    partp  = (float*)(ws + OFF_PART);
    float*    ah32   = (float*)(ws + OFF_AH);
    float*    at32   = (float*)(ws + OFF_AT);
    unsigned* flag   = (unsigned*)(ws + OFF_FLAG);
    __bf16*   whh    = (__bf16*)(ws + OFF_WHH);
    __bf16*   wth    = (__bf16*)(ws + OFF_WTH);
    unsigned* cursH  = (unsigned*)(ws + OFF_CURSH);
    unsigned* cursT  = (unsigned*)(ws + OFF_CURST);
    float4*   ex4    = (float4*)(ws + OFF_EX);

    k_init<<<161, 256, 0, stream>>>((const unsigned*)xe, ahp, atp, wh, wt, flag, ah32, at32,
                                     whh, wth, (unsigned*)(ws + OFF_SUMS));
    k_gemm<<<512, 512, 0, stream>>>(xe, flag, whh, wth, ah32, at32,
                                    xh, xt, (float2*)sp, (float2*)dp);
    k_edge<<<NBE, 1024, 0, stream>>>(src, dst, rel, sp, dp, sums, histH, histT, ex4);
    k_scan2<<<1, 1024, 0, stream>>>(histH, histT, sums, baseH, baseT, cursH, cursT, invs);
    k_mkrec<<<NBE, 1024, 0, stream>>>(src, dst, rel, ex4, (const float4*)invs, cursH, cursT, recH, recT);
    k_accR<<<NBK, 256, 0, stream>>>(recH, recT, baseH, baseT, xh, xt, partp);
    k_out<<<(NR * KRH + 255) / 256, 256, 0, stream>>>(partp, flag, d_out);
}

// Round 10
// 247.225 us; speedup vs baseline: 1.0975x; 1.0975x over previous
//
#include <hip/hip_runtime.h>
#include <hip/hip_bf16.h>

#define NN 50000      // nodes
#define NE 800000     // edges
#define NR 500        // relations
#define KEH 256       // input feat dim
#define KRH 128       // proj feat dim
#define NSB 8         // node super-bins (node / 6250), aligned to 8 XCDs
#define SBW 6250      // super-bin width
#define NBK (NR*NSB)  // 4000 buckets
#define NBE 256       // edge-pass blocks (k_edge / k_mkrec)
#define EPB (NE/NBE)  // 3125 edges per block
#define NTILE 3125    // 16-row GEMM tiles (50000/16 exactly)

typedef __attribute__((ext_vector_type(8))) __bf16 bf16x8;
typedef __attribute__((ext_vector_type(4))) float f32x4;

// ---- workspace layout (bytes, 16B aligned), total ~63.4 MiB ----
#define OFF_XH     0UL            // [NN][128] bf16
#define OFF_XT     12800000UL     // [NN][128] bf16
#define OFF_SP     25600000UL     // [NN] float4
#define OFF_DP     26400000UL     // [NN] float4
#define OFF_SUMS   27200000UL     // [NR*4] f32 (8000 B)
#define OFF_HISTH  27208000UL     // [NBK] u32 totals (16000 B)
#define OFF_HISTT  27224000UL     // [NBK] u32 totals (16000 B)
// zero region SUMS..HISTT = 40000 B = 10000 u32
#define OFF_INVS   27240000UL     // [NR*4] f32
#define OFF_BASEH  27248000UL     // [NBK+1] u32 (16016 B)
#define OFF_BASET  27264016UL     // [NBK+1] u32
#define OFF_RECH   27312032UL     // [NE] uint2 (node, w1) 6.4 MB
#define OFF_RECT   33712032UL     // [NE] uint2 (node, w2) 6.4 MB
#define OFF_PART   40112032UL     // [NBK][128] f32 partials (2.048 MB)
#define OFF_AH     42160032UL     // [256] f32
#define OFF_AT     42161056UL     // [256] f32
#define OFF_FLAG   42162080UL     // u32
#define OFF_WHH    42162144UL     // [128][256] bf16, FRAGMENT order
#define OFF_WHL    42227680UL     // (unused since compensation dropped)
#define OFF_WTH    42293216UL
#define OFF_WTL    42358752UL     // (unused)
#define OFF_HPBH   42424288UL     // [NBE][NBK] u32 per-block hist/offsets 4.096 MB
#define OFF_HPBT   46520288UL     // [NBE][NBK] u32                       4.096 MB
#define OFF_EX     50616288UL     // [NE] float4 exp-scores 12.8 MB
// end 63,416,288

__device__ __forceinline__ int clampi(int v, int hi) {  // [0, hi)
    v = v < 0 ? 0 : v;
    return v >= hi ? hi - 1 : v;
}

// Wave-replicated dtype sniff (see round-8 notes).
__device__ __forceinline__ int sniff_isbf(const unsigned* xe_raw) {
    int lane = threadIdx.x & 63;
    unsigned w = xe_raw[lane];
    unsigned ex = (w >> 7) & 0xFFu;
    bool hit = (ex >= 115u && ex <= 131u);
    return __popcll(__ballot(hit)) >= 32;
}

// block 0: flag + a_h/a_t convert. blocks 1..128: weight -> FRAGMENT order
// (bf16 cast, no error-compensation split). blocks 129+: zero sums + histH +
// histT (10000 u32).
// Frag order: out index o = ((ct*8+ks)*64 + q*16 + c)*8 + e  holds
// w[ct*16+c][ks*32+q*8+e]  — so lane l=q*16+c of fragment (ct,ks) reads its
// 8 contiguous bf16 (col=l&15, k-seg=(l>>4)*8) as one 16B chunk, and the
// LDS stage is a linear 64KB copy.
__global__ __launch_bounds__(256) void k_init(const unsigned* __restrict__ xe_raw,
                                              const void* __restrict__ ah_in, const void* __restrict__ at_in,
                                              const void* __restrict__ wh, const void* __restrict__ wt,
                                              unsigned* __restrict__ flag, float* __restrict__ ah32,
                                              float* __restrict__ at32,
                                              __bf16* __restrict__ whh, __bf16* __restrict__ wth,
                                              unsigned* __restrict__ zero1) {
    int isbf = sniff_isbf(xe_raw);
    int t = threadIdx.x;
    if (blockIdx.x == 0) {
        if (t == 0) flag[0] = (unsigned)isbf;
        ah32[t] = isbf ? __bfloat162float(((const __hip_bfloat16*)ah_in)[t]) : ((const float*)ah_in)[t];
        at32[t] = isbf ? __bfloat162float(((const __hip_bfloat16*)at_in)[t]) : ((const float*)at_in)[t];
    } else if (blockIdx.x <= 128) {
        int o = (blockIdx.x - 1) * 256 + t;   // [0, 32768) frag-order output idx
        int e = o & 7, c = (o >> 3) & 15, q = (o >> 7) & 3, ks = (o >> 9) & 7, ct = o >> 12;
        int i = (ct * 16 + c) * KEH + ks * 32 + q * 8 + e;   // row-major source
        if (isbf) {
            whh[o] = ((const __bf16*)wh)[i];
            wth[o] = ((const __bf16*)wt)[i];
        } else {
            whh[o] = (__bf16)((const float*)wh)[i];
            wth[o] = (__bf16)((const float*)wt)[i];
        }
    } else {
        int stride = (gridDim.x - 129) * 256;
        for (int i = (blockIdx.x - 129) * 256 + t; i < 10000; i += stride) zero1[i] = 0u;
    }
}

// Split-phase GEMM + fused per-node scores, single-term bf16 MFMA.
// Grid 512 x 512 thr (8 waves; 64KB LDS -> 2 blocks/CU resident).
// phase = bid&1 (0=H->xh, 1=T->xt). Block stages its phase's weight matrix
// (64 KB, linear copy — k_init wrote fragment order) into LDS once; waves
// grid-stride over 16-row tiles: 8 A-frag loads (fp32: 16 float4 + bf16
// cast; measured: absmax identical to the compensated version), 64
// {ds_read_b128 + MFMA}, epilogue: xh/xt stores + 4 score dot-products/row
// via 16-lane shfl_xor, written to the phase's disjoint float2 halves of
// sp/dp.
__global__ __launch_bounds__(512, 4) void k_gemm(const void* __restrict__ xe,
                                              const unsigned* __restrict__ flag,
                                              const __bf16* __restrict__ whh, const __bf16* __restrict__ wth,
                                              const float* __restrict__ ah, const float* __restrict__ at,
                                              __hip_bfloat16* __restrict__ xh, __hip_bfloat16* __restrict__ xt,
                                              float2* __restrict__ sp2, float2* __restrict__ dp2) {
    __shared__ uint4 lb[4096];    // 64 KiB: this phase's weight matrix, frag order
    const int t = threadIdx.x, lane = t & 63, wave = t >> 6;
    const int l16 = lane & 15, quad = lane >> 4;
    const int ph = blockIdx.x & 1;
    const int isbf = (int)flag[0];
    const __bf16* wfh = ph ? wth : whh;

    {   // linear 64 KB stage: 512 thr x 8 x 16B
        const uint4* wsrc = (const uint4*)wfh;
        #pragma unroll
        for (int i = 0; i < 8; ++i) lb[i * 512 + t] = wsrc[i * 512 + t];
    }
    __syncthreads();

    __hip_bfloat16* out = ph ? xt : xh;
    for (int tile = (int)(blockIdx.x >> 1) * 8 + wave; tile < NTILE; tile += 2048) {
        const int row = tile * 16 + l16;       // this lane's A row
        bf16x8 a[8];
        if (isbf) {
            const __bf16* xb = (const __bf16*)xe + (size_t)row * KEH;
            #pragma unroll
            for (int ks = 0; ks < 8; ++ks)
                a[ks] = *(const bf16x8*)(xb + ks * 32 + quad * 8);
        } else {
            const float* xf = (const float*)xe + (size_t)row * KEH;
            #pragma unroll
            for (int ks = 0; ks < 8; ++ks) {
                const float* p = xf + ks * 32 + quad * 8;
                float4 u0 = *(const float4*)p, u1 = *(const float4*)(p + 4);
                a[ks][0] = (__bf16)u0.x; a[ks][1] = (__bf16)u0.y;
                a[ks][2] = (__bf16)u0.z; a[ks][3] = (__bf16)u0.w;
                a[ks][4] = (__bf16)u1.x; a[ks][5] = (__bf16)u1.y;
                a[ks][6] = (__bf16)u1.z; a[ks][7] = (__bf16)u1.w;
            }
        }

        f32x4 acc[8];
        #pragma unroll
        for (int ct = 0; ct < 8; ++ct) acc[ct] = (f32x4){0.f, 0.f, 0.f, 0.f};
        #pragma unroll
        for (int ks = 0; ks < 8; ++ks)
            #pragma unroll
            for (int ct = 0; ct < 8; ++ct)
                acc[ct] = __builtin_amdgcn_mfma_f32_16x16x32_bf16(
                    a[ks], *(const bf16x8*)&lb[(ct * 8 + ks) * 64 + lane], acc[ct], 0, 0, 0);

        // ---- epilogue: store projected rows + fused scores ----
        float s0[4] = {0.f,0.f,0.f,0.f}, s1[4] = {0.f,0.f,0.f,0.f};
        float s2[4] = {0.f,0.f,0.f,0.f}, s3[4] = {0.f,0.f,0.f,0.f};
        #pragma unroll
        for (int ct = 0; ct < 8; ++ct) {
            int c = ct * 16 + l16;
            float va0 = ah[c], va1 = ah[128 + c];
            float vb0 = at[c], vb1 = at[128 + c];
            #pragma unroll
            for (int jj = 0; jj < 4; ++jj) {
                float v = acc[ct][jj];
                s0[jj] = fmaf(v, va0, s0[jj]);
                s1[jj] = fmaf(v, va1, s1[jj]);
                s2[jj] = fmaf(v, vb0, s2[jj]);
                s3[jj] = fmaf(v, vb1, s3[jj]);
                out[(size_t)(tile * 16 + quad * 4 + jj) * KRH + c] = __float2bfloat16(v);
            }
        }
        #pragma unroll
        for (int off = 8; off; off >>= 1)
            #pragma unroll
            for (int jj = 0; jj < 4; ++jj) {
                s0[jj] += __shfl_xor(s0[jj], off);
                s1[jj] += __shfl_xor(s1[jj], off);
                s2[jj] += __shfl_xor(s2[jj], off);
                s3[jj] += __shfl_xor(s3[jj], off);
            }
        if (l16 == 0) {
            // sp = (s_hh0, s_hh1, s_th0, s_th1); dp = (s_tt0, s_tt1, s_ht0, s_ht1)
            #pragma unroll
            for (int jj = 0; jj < 4; ++jj) {
                int n = tile * 16 + quad * 4 + jj;
                if (ph == 0) {
                    sp2[n * 2 + 0] = make_float2(s0[jj], s1[jj]);   // s_hh
                    dp2[n * 2 + 1] = make_float2(s2[jj], s3[jj]);   // s_ht
                } else {
                    sp2[n * 2 + 1] = make_float2(s0[jj], s1[jj]);   // s_th
                    dp2[n * 2 + 0] = make_float2(s2[jj], s3[jj]);   // s_tt
                }
            }
        }
    }
}

__device__ __forceinline__ float eexp(float x) {
    x = x > 0.f ? x : 0.01f * x;
    x = fminf(x, 50.f);
    return __expf(x);
}

// Per edge (contiguous 3125-edge range per block, 1024 thr = 16 waves/CU):
// 4 exp scores -> ex4 store + LDS segment sums + (rel,sbin) histograms ->
// global totals (atomic) AND this block's private hpb row (non-atomic).
// Round-9 lesson: the per-block hpb windows are kept — they provide write
// run-locality and LDS-local cursor bumps in k_mkrec (global atomic cursors
// cost 7x write amplification + 80us serialization).
__global__ __launch_bounds__(1024) void k_edge(const int* __restrict__ src, const int* __restrict__ dst,
                                               const int* __restrict__ rel,
                                               const float4* __restrict__ sp, const float4* __restrict__ dp,
                                               float* __restrict__ sums,
                                               unsigned* __restrict__ histH, unsigned* __restrict__ histT,
                                               unsigned* __restrict__ hpbH, unsigned* __restrict__ hpbT,
                                               float4* __restrict__ ex4) {
    __shared__ float ls[NR * 4];
    __shared__ unsigned lhH[NBK], lhT[NBK];
    int t = threadIdx.x;
    for (int i = t; i < NR * 4; i += 1024) ls[i] = 0.f;
    for (int i = t; i < NBK; i += 1024) { lhH[i] = 0u; lhT[i] = 0u; }
    __syncthreads();
    unsigned lo = blockIdx.x * EPB, hi = lo + EPB;
    for (unsigned e = lo + t; e < hi; e += 1024) {
        int s = clampi(src[e], NN), d = clampi(dst[e], NN), r = clampi(rel[e], NR);
        float4 a = sp[s], b = dp[d];
        float4 ex;
        ex.x = eexp(a.x + b.x); ex.y = eexp(a.y + b.y);
        ex.z = eexp(a.z + b.z); ex.w = eexp(a.w + b.w);
        ex4[e] = ex;
        atomicAdd(&ls[r*4+0], ex.x);
        atomicAdd(&ls[r*4+1], ex.y);
        atomicAdd(&ls[r*4+2], ex.z);
        atomicAdd(&ls[r*4+3], ex.w);
        atomicAdd(&lhH[r * NSB + s / SBW], 1u);
        atomicAdd(&lhT[r * NSB + d / SBW], 1u);
    }
    __syncthreads();
    for (int i = t; i < NR * 4; i += 1024)
        if (ls[i] != 0.f) atomicAdd(&sums[i], ls[i]);
    size_t row = (size_t)blockIdx.x * NBK;
    for (int i = t; i < NBK; i += 1024) {
        unsigned cH = lhH[i], cT = lhT[i];
        hpbH[row + i] = cH;
        hpbT[row + i] = cT;
        if (cH) atomicAdd(&histH[i], cH);
        if (cT) atomicAdd(&histT[i], cT);
    }
}

// Scan both 4000-bin total histograms -> bucket bases; invs = 1/(sums+eps).
// Wave-level shfl_up scan (2 barriers/pass vs 20 Hillis-Steele).
__global__ __launch_bounds__(1024) void k_scan2(const unsigned* __restrict__ histH,
                                                const unsigned* __restrict__ histT,
                                                const float* __restrict__ sums,
                                                unsigned* __restrict__ baseH, unsigned* __restrict__ baseT,
                                                float* __restrict__ invs) {
    __shared__ unsigned wsum[16];
    int t = threadIdx.x, lane = t & 63, wv = t >> 6;
    for (int pass = 0; pass < 2; ++pass) {
        const unsigned* h = pass ? histT : histH;
        unsigned* base = pass ? baseT : baseH;
        int j0 = t * 4;
        unsigned v[4], s = 0;
        #pragma unroll
        for (int k = 0; k < 4; ++k) { v[k] = (j0 + k < NBK) ? h[j0 + k] : 0u; s += v[k]; }
        unsigned inc = s;                       // inclusive wave scan
        #pragma unroll
        for (int d = 1; d < 64; d <<= 1) {
            unsigned u = __shfl_up(inc, d);
            if (lane >= d) inc += u;
        }
        if (lane == 63) wsum[wv] = inc;
        __syncthreads();
        unsigned wbase = 0;
        for (int i = 0; i < wv; ++i) wbase += wsum[i];
        unsigned run = wbase + inc - s;         // exclusive prefix
        #pragma unroll
        for (int k = 0; k < 4; ++k) {
            if (j0 + k < NBK) { base[j0 + k] = run; run += v[k]; }
        }
        if (t == 1023) base[NBK] = wbase + inc;
        __syncthreads();                        // wsum reuse next pass
    }
    for (int i = t; i < NR * 4; i += 1024) invs[i] = 1.f / (sums[i] + 1e-16f);
}

// Column scan: per (pass,bin), exclusive-scan the NBE per-block counts and add
// the bucket base -> hpb becomes each block's exact write offset. No atomics.
// Wave-level shfl_up scan (1 barrier vs 16).
__global__ __launch_bounds__(NBE) void k_colscan(unsigned* __restrict__ hpbH, unsigned* __restrict__ hpbT,
                                                 const unsigned* __restrict__ baseH,
                                                 const unsigned* __restrict__ baseT) {
    __shared__ unsigned wsum[4];
    int b = blockIdx.x;              // [0, 2*NBK)
    int pass = b >= NBK;
    int bin = pass ? b - NBK : b;
    unsigned* h = pass ? hpbT : hpbH;
    unsigned basev = (pass ? baseT : baseH)[bin];
    int t = threadIdx.x, lane = t & 63, wv = t >> 6;
    unsigned v = h[(size_t)t * NBK + bin];
    unsigned inc = v;
    #pragma unroll
    for (int d = 1; d < 64; d <<= 1) {
        unsigned u = __shfl_up(inc, d);
        if (lane >= d) inc += u;
    }
    if (lane == 63) wsum[wv] = inc;
    __syncthreads();
    unsigned wbase = 0;
    for (int i = 0; i < wv; ++i) wbase += wsum[i];
    h[(size_t)t * NBK + bin] = basev + wbase + inc - v;
}

// Single-pass scatter (1024 thr): weights from streamed ex4 (no gathers, no
// exp); LDS cursors from precomputed per-block offsets.
__global__ __launch_bounds__(1024) void k_mkrec(const int* __restrict__ src, const int* __restrict__ dst,
                                                const int* __restrict__ rel,
                                                const float4* __restrict__ ex4,
                                                const float4* __restrict__ invs4,
                                                const unsigned* __restrict__ hpbH, const unsigned* __restrict__ hpbT,
                                                uint2* __restrict__ recH, uint2* __restrict__ recT) {
    __shared__ unsigned lcH[NBK], lcT[NBK];
    int t = threadIdx.x;
    size_t row = (size_t)blockIdx.x * NBK;
    for (int i = t; i < NBK; i += 1024) { lcH[i] = hpbH[row + i]; lcT[i] = hpbT[row + i]; }
    __syncthreads();
    unsigned lo = blockIdx.x * EPB, hi = lo + EPB;
    for (unsigned e = lo + t; e < hi; e += 1024) {
        int s = clampi(src[e], NN), d = clampi(dst[e], NN), r = clampi(rel[e], NR);
        float4 ex = ex4[e];
        float4 iv = invs4[r];
        float w1 = ex.x * iv.x + ex.y * iv.y;
        float w2 = ex.z * iv.z + ex.w * iv.w;
        unsigned pH = atomicAdd(&lcH[r * NSB + s / SBW], 1u);
        unsigned pT = atomicAdd(&lcT[r * NSB + d / SBW], 1u);
        if (pH < NE) recH[pH] = make_uint2((unsigned)s, __float_as_uint(w1));
        if (pT < NE) recT[pT] = make_uint2((unsigned)d, __float_as_uint(w2));
    }
}

// One block per (rel,sbin) bucket. Chunked rec staging (256/LDS burst), then
// 16-lane-group gather: each wave processes 4 records/iter, 8 cols/lane via
// one b128 load — ~6 wave-instr/record vs 13 for the old 64-lane/u32 shape
// (round-7 pmc: VALUBusy 75%, MfmaUtil 0 -> VALU-issue-bound). Group reduce:
// shfl_xor(16,32) then LDS cross-wave sum.
__global__ __launch_bounds__(256) void k_accR(const uint2* __restrict__ recH, const uint2* __restrict__ recT,
                                              const unsigned* __restrict__ baseH, const unsigned* __restrict__ baseT,
                                              const __hip_bfloat16* __restrict__ xh,
                                              const __hip_bfloat16* __restrict__ xt,
                                              float* __restrict__ part) {
    __shared__ float red[3][128];
    __shared__ uint2 lrec[256];
    int b = blockIdx.x;
    int t = threadIdx.x, lane = t & 63, wv = t >> 6;
    int l16 = lane & 15, g = lane >> 4;      // col sub-slice, record subgroup
    float az[8];
    #pragma unroll
    for (int k = 0; k < 8; ++k) az[k] = 0.f;

    for (int pass = 0; pass < 2; ++pass) {
        const uint2* rec = pass ? recT : recH;
        const unsigned* base = pass ? baseT : baseH;
        const uint4* xs = (const uint4*)(pass ? xt : xh);   // row = 16 uint4
        unsigned b0 = base[b];
        unsigned cnt = base[b + 1] - b0;
        if (cnt > NE) cnt = 0;        // poison guard
        for (unsigned cb = 0; cb < cnt; cb += 256u) {
            unsigned cn = cnt - cb; if (cn > 256u) cn = 256u;
            __syncthreads();                       // prior chunk readers done
            if ((unsigned)t < cn) lrec[t] = rec[b0 + cb + t];
            __syncthreads();
            // wave wv, group g covers records j = wv*4+g, +16, ...
            for (unsigned j = (unsigned)(wv * 4 + g); j < cn; j += 16u) {
                uint2 v = lrec[j];
                unsigned nd = v.x < NN ? v.x : 0u;     // poison guard
                float w = __uint_as_float(v.y);
                uint4 u = xs[(size_t)nd * 16 + l16];
                az[0] = fmaf(w, __uint_as_float(u.x << 16),          az[0]);
                az[1] = fmaf(w, __uint_as_float(u.x & 0xffff0000u),  az[1]);
                az[2] = fmaf(w, __uint_as_float(u.y << 16),          az[2]);
                az[3] = fmaf(w, __uint_as_float(u.y & 0xffff0000u),  az[3]);
                az[4] = fmaf(w, __uint_as_float(u.z << 16),          az[4]);
                az[5] = fmaf(w, __uint_as_float(u.z & 0xffff0000u),  az[5]);
                az[6] = fmaf(w, __uint_as_float(u.w << 16),          az[6]);
                az[7] = fmaf(w, __uint_as_float(u.w & 0xffff0000u),  az[7]);
            }
        }
    }
    // reduce the 4 record-subgroups: lanes 0-15 end with column totals
    #pragma unroll
    for (int k = 0; k < 8; ++k) {
        az[k] += __shfl_xor(az[k], 16);
        az[k] += __shfl_xor(az[k], 32);
    }
    __syncthreads();                  // lrec dead; red reuse safe
    if (wv > 0 && lane < 16) {
        #pragma unroll
        for (int k = 0; k < 8; ++k) red[wv - 1][l16 * 8 + k] = az[k];
    }
    __syncthreads();
    if (wv == 0 && lane < 16) {
        #pragma unroll
        for (int k = 0; k < 8; ++k) {
            float s = az[k] + red[0][l16 * 8 + k] + red[1][l16 * 8 + k] + red[2][l16 * 8 + k];
            part[(size_t)b * KRH + l16 * 8 + k] = s;
        }
    }
}

// out[r][c] = 0.25 * sum_sbin part[r*8+sbin][c]; dtype follows input.
__global__ __launch_bounds__(256) void k_out(const float* __restrict__ part,
                                             const unsigned* __restrict__ flag, void* __restrict__ out) {
    int i = blockIdx.x * 256 + threadIdx.x;
    if (i < NR * KRH) {
        int r = i >> 7, c = i & 127;
        float v = 0.f;
        for (int s = 0; s < NSB; ++s) v += part[(size_t)(r * NSB + s) * KRH + c];
        v *= 0.25f;                   // / num_heads(2) / 2
        if (!isfinite(v)) v = 0.f;
        if (flag[0]) ((__hip_bfloat16*)out)[i] = __float2bfloat16(v);
        else         ((float*)out)[i] = v;
    }
}

extern "C" void kernel_launch(void* const* d_in, const int* in_sizes, int n_in,
                              void* d_out, int out_size, void* d_ws, size_t ws_size,
                              hipStream_t stream) {
    const void* xe  = d_in[0];
    const int* eidx = (const int*)d_in[1];
    const int* rel  = (const int*)d_in[2];
    const void* wh  = d_in[3];
    const void* wt  = d_in[4];
    const void* ahp = d_in[5];
    const void* atp = d_in[6];

    const int* src = eidx;
    const int* dst = eidx + NE;

    char* ws = (char*)d_ws;
    __hip_bfloat16* xh = (__hip_bfloat16*)(ws + OFF_XH);
    __hip_bfloat16* xt = (__hip_bfloat16*)(ws + OFF_XT);
    float4*   sp     = (float4*)(ws + OFF_SP);
    float4*   dp     = (float4*)(ws + OFF_DP);
    float*    sums   = (float*)(ws + OFF_SUMS);
    unsigned* histH  = (unsigned*)(ws + OFF_HISTH);
    unsigned* histT  = (unsigned*)(ws + OFF_HISTT);
    float*    invs   = (float*)(ws + OFF_INVS);
    unsigned* baseH  = (unsigned*)(ws + OFF_BASEH);
    unsigned* baseT  = (unsigned*)(ws + OFF_BASET);
    uint2*    recH   = (uint2*)(ws + OFF_RECH);
    uint2*    recT   = (uint2*)(ws + OFF_RECT);
    float*    partp  = (float*)(ws + OFF_PART);
    float*    ah32   = (float*)(ws + OFF_AH);
    float*    at32   = (float*)(ws + OFF_AT);
    unsigned* flag   = (unsigned*)(ws + OFF_FLAG);
    __bf16*   whh    = (__bf16*)(ws + OFF_WHH);
    __bf16*   wth    = (__bf16*)(ws + OFF_WTH);
    unsigned* hpbH   = (unsigned*)(ws + OFF_HPBH);
    unsigned* hpbT   = (unsigned*)(ws + OFF_HPBT);
    float4*   ex4    = (float4*)(ws + OFF_EX);

    k_init<<<161, 256, 0, stream>>>((const unsigned*)xe, ahp, atp, wh, wt, flag, ah32, at32,
                                     whh, wth, (unsigned*)(ws + OFF_SUMS));
    k_gemm<<<512, 512, 0, stream>>>(xe, flag, whh, wth, ah32, at32,
                                    xh, xt, (float2*)sp, (float2*)dp);
    k_edge<<<NBE, 1024, 0, stream>>>(src, dst, rel, sp, dp, sums, histH, histT, hpbH, hpbT, ex4);
    k_scan2<<<1, 1024, 0, stream>>>(histH, histT, sums, baseH, baseT, invs);
    k_colscan<<<2 * NBK, NBE, 0, stream>>>(hpbH, hpbT, baseH, baseT);
    k_mkrec<<<NBE, 1024, 0, stream>>>(src, dst, rel, ex4, (const float4*)invs, hpbH, hpbT, recH, recT);
    k_accR<<<NBK, 256, 0, stream>>>(recH, recT, baseH, baseT, xh, xt, partp);
    k_out<<<(NR * KRH + 255) / 256, 256, 0, stream>>>(partp, flag, d_out);
}

// Round 11
// 238.467 us; speedup vs baseline: 1.1378x; 1.0367x over previous
//
#include <hip/hip_runtime.h>
#include <hip/hip_bf16.h>

#define NN 50000      // nodes
#define NE 800000     // edges
#define NR 500        // relations
#define KEH 256       // input feat dim
#define KRH 128       // proj feat dim
#define NSB 8         // node super-bins (node / 6250), aligned to 8 XCDs
#define SBW 6250      // super-bin width
#define NBK (NR*NSB)  // 4000 buckets
#define NBE 256       // edge-pass blocks (k_edge / k_mkrec)
#define EPB (NE/NBE)  // 3125 edges per block
#define NTILE 3125    // 16-row GEMM tiles (50000/16 exactly)
#define CSB 16        // k_colscan bins per block (NBK/CSB = 250 blocks/pass)

typedef __attribute__((ext_vector_type(8))) __bf16 bf16x8;
typedef __attribute__((ext_vector_type(4))) float f32x4;

// ---- workspace layout (bytes, 16B aligned), total ~63.4 MiB ----
#define OFF_XH     0UL            // [NN][128] bf16
#define OFF_XT     12800000UL     // [NN][128] bf16
#define OFF_SP     25600000UL     // [NN] float4
#define OFF_DP     26400000UL     // [NN] float4
#define OFF_SUMS   27200000UL     // [NR*4] f32 (8000 B)
#define OFF_HISTH  27208000UL     // [NBK] u32 totals (16000 B)
#define OFF_HISTT  27224000UL     // [NBK] u32 totals (16000 B)
// zero region SUMS..HISTT = 40000 B = 10000 u32
#define OFF_INVS   27240000UL     // [NR*4] f32
#define OFF_BASEH  27248000UL     // [NBK+1] u32 (16016 B)
#define OFF_BASET  27264016UL     // [NBK+1] u32
#define OFF_RECH   27312032UL     // [NE] uint2 (node, w1) 6.4 MB
#define OFF_RECT   33712032UL     // [NE] uint2 (node, w2) 6.4 MB
#define OFF_PART   40112032UL     // [NBK][128] f32 partials (2.048 MB)
#define OFF_AH     42160032UL     // [256] f32
#define OFF_AT     42161056UL     // [256] f32
#define OFF_FLAG   42162080UL     // u32
#define OFF_WHH    42162144UL     // [128][256] bf16, FRAGMENT order
#define OFF_WHL    42227680UL     // (unused since compensation dropped)
#define OFF_WTH    42293216UL
#define OFF_WTL    42358752UL     // (unused)
#define OFF_HPBH   42424288UL     // [NBE][NBK] u32 per-block hist/offsets 4.096 MB
#define OFF_HPBT   46520288UL     // [NBE][NBK] u32                       4.096 MB
// OFF_EX dropped (round-11): k_mkrec recomputes exp from L2-hot sp/dp
// end 63,416,288

__device__ __forceinline__ int clampi(int v, int hi) {  // [0, hi)
    v = v < 0 ? 0 : v;
    return v >= hi ? hi - 1 : v;
}

// Wave-replicated dtype sniff (see round-8 notes).
__device__ __forceinline__ int sniff_isbf(const unsigned* xe_raw) {
    int lane = threadIdx.x & 63;
    unsigned w = xe_raw[lane];
    unsigned ex = (w >> 7) & 0xFFu;
    bool hit = (ex >= 115u && ex <= 131u);
    return __popcll(__ballot(hit)) >= 32;
}

// block 0: flag + a_h/a_t convert. blocks 1..128: weight -> FRAGMENT order
// (bf16 cast, no error-compensation split). blocks 129+: zero sums + histH +
// histT (10000 u32).
// Frag order: out index o = ((ct*8+ks)*64 + q*16 + c)*8 + e  holds
// w[ct*16+c][ks*32+q*8+e]  — so lane l=q*16+c of fragment (ct,ks) reads its
// 8 contiguous bf16 (col=l&15, k-seg=(l>>4)*8) as one 16B chunk, and the
// LDS stage is a linear 64KB copy.
__global__ __launch_bounds__(256) void k_init(const unsigned* __restrict__ xe_raw,
                                              const void* __restrict__ ah_in, const void* __restrict__ at_in,
                                              const void* __restrict__ wh, const void* __restrict__ wt,
                                              unsigned* __restrict__ flag, float* __restrict__ ah32,
                                              float* __restrict__ at32,
                                              __bf16* __restrict__ whh, __bf16* __restrict__ wth,
                                              unsigned* __restrict__ zero1) {
    int isbf = sniff_isbf(xe_raw);
    int t = threadIdx.x;
    if (blockIdx.x == 0) {
        if (t == 0) flag[0] = (unsigned)isbf;
        ah32[t] = isbf ? __bfloat162float(((const __hip_bfloat16*)ah_in)[t]) : ((const float*)ah_in)[t];
        at32[t] = isbf ? __bfloat162float(((const __hip_bfloat16*)at_in)[t]) : ((const float*)at_in)[t];
    } else if (blockIdx.x <= 128) {
        int o = (blockIdx.x - 1) * 256 + t;   // [0, 32768) frag-order output idx
        int e = o & 7, c = (o >> 3) & 15, q = (o >> 7) & 3, ks = (o >> 9) & 7, ct = o >> 12;
        int i = (ct * 16 + c) * KEH + ks * 32 + q * 8 + e;   // row-major source
        if (isbf) {
            whh[o] = ((const __bf16*)wh)[i];
            wth[o] = ((const __bf16*)wt)[i];
        } else {
            whh[o] = (__bf16)((const float*)wh)[i];
            wth[o] = (__bf16)((const float*)wt)[i];
        }
    } else {
        int stride = (gridDim.x - 129) * 256;
        for (int i = (blockIdx.x - 129) * 256 + t; i < 10000; i += stride) zero1[i] = 0u;
    }
}

// Split-phase GEMM + fused per-node scores, single-term bf16 MFMA.
// Grid 512 x 512 thr (8 waves; 64KB LDS -> 2 blocks/CU resident).
// phase = bid&1 (0=H->xh, 1=T->xt). Block stages its phase's weight matrix
// (64 KB, linear copy — k_init wrote fragment order) into LDS once; waves
// grid-stride over 16-row tiles: 8 A-frag loads (fp32: 16 float4 + bf16
// cast; measured: absmax identical to the compensated version), 64
// {ds_read_b128 + MFMA}, epilogue: xh/xt stores + 4 score dot-products/row
// via 16-lane shfl_xor, written to the phase's disjoint float2 halves of
// sp/dp.
__global__ __launch_bounds__(512, 4) void k_gemm(const void* __restrict__ xe,
                                              const unsigned* __restrict__ flag,
                                              const __bf16* __restrict__ whh, const __bf16* __restrict__ wth,
                                              const float* __restrict__ ah, const float* __restrict__ at,
                                              __hip_bfloat16* __restrict__ xh, __hip_bfloat16* __restrict__ xt,
                                              float2* __restrict__ sp2, float2* __restrict__ dp2) {
    __shared__ uint4 lb[4096];    // 64 KiB: this phase's weight matrix, frag order
    const int t = threadIdx.x, lane = t & 63, wave = t >> 6;
    const int l16 = lane & 15, quad = lane >> 4;
    const int ph = blockIdx.x & 1;
    const int isbf = (int)flag[0];
    const __bf16* wfh = ph ? wth : whh;

    {   // linear 64 KB stage: 512 thr x 8 x 16B
        const uint4* wsrc = (const uint4*)wfh;
        #pragma unroll
        for (int i = 0; i < 8; ++i) lb[i * 512 + t] = wsrc[i * 512 + t];
    }
    __syncthreads();

    __hip_bfloat16* out = ph ? xt : xh;
    for (int tile = (int)(blockIdx.x >> 1) * 8 + wave; tile < NTILE; tile += 2048) {
        const int row = tile * 16 + l16;       // this lane's A row
        bf16x8 a[8];
        if (isbf) {
            const __bf16* xb = (const __bf16*)xe + (size_t)row * KEH;
            #pragma unroll
            for (int ks = 0; ks < 8; ++ks)
                a[ks] = *(const bf16x8*)(xb + ks * 32 + quad * 8);
        } else {
            const float* xf = (const float*)xe + (size_t)row * KEH;
            #pragma unroll
            for (int ks = 0; ks < 8; ++ks) {
                const float* p = xf + ks * 32 + quad * 8;
                float4 u0 = *(const float4*)p, u1 = *(const float4*)(p + 4);
                a[ks][0] = (__bf16)u0.x; a[ks][1] = (__bf16)u0.y;
                a[ks][2] = (__bf16)u0.z; a[ks][3] = (__bf16)u0.w;
                a[ks][4] = (__bf16)u1.x; a[ks][5] = (__bf16)u1.y;
                a[ks][6] = (__bf16)u1.z; a[ks][7] = (__bf16)u1.w;
            }
        }

        f32x4 acc[8];
        #pragma unroll
        for (int ct = 0; ct < 8; ++ct) acc[ct] = (f32x4){0.f, 0.f, 0.f, 0.f};
        #pragma unroll
        for (int ks = 0; ks < 8; ++ks)
            #pragma unroll
            for (int ct = 0; ct < 8; ++ct)
                acc[ct] = __builtin_amdgcn_mfma_f32_16x16x32_bf16(
                    a[ks], *(const bf16x8*)&lb[(ct * 8 + ks) * 64 + lane], acc[ct], 0, 0, 0);

        // ---- epilogue: store projected rows + fused scores ----
        float s0[4] = {0.f,0.f,0.f,0.f}, s1[4] = {0.f,0.f,0.f,0.f};
        float s2[4] = {0.f,0.f,0.f,0.f}, s3[4] = {0.f,0.f,0.f,0.f};
        #pragma unroll
        for (int ct = 0; ct < 8; ++ct) {
            int c = ct * 16 + l16;
            float va0 = ah[c], va1 = ah[128 + c];
            float vb0 = at[c], vb1 = at[128 + c];
            #pragma unroll
            for (int jj = 0; jj < 4; ++jj) {
                float v = acc[ct][jj];
                s0[jj] = fmaf(v, va0, s0[jj]);
                s1[jj] = fmaf(v, va1, s1[jj]);
                s2[jj] = fmaf(v, vb0, s2[jj]);
                s3[jj] = fmaf(v, vb1, s3[jj]);
                out[(size_t)(tile * 16 + quad * 4 + jj) * KRH + c] = __float2bfloat16(v);
            }
        }
        #pragma unroll
        for (int off = 8; off; off >>= 1)
            #pragma unroll
            for (int jj = 0; jj < 4; ++jj) {
                s0[jj] += __shfl_xor(s0[jj], off);
                s1[jj] += __shfl_xor(s1[jj], off);
                s2[jj] += __shfl_xor(s2[jj], off);
                s3[jj] += __shfl_xor(s3[jj], off);
            }
        if (l16 == 0) {
            // sp = (s_hh0, s_hh1, s_th0, s_th1); dp = (s_tt0, s_tt1, s_ht0, s_ht1)
            #pragma unroll
            for (int jj = 0; jj < 4; ++jj) {
                int n = tile * 16 + quad * 4 + jj;
                if (ph == 0) {
                    sp2[n * 2 + 0] = make_float2(s0[jj], s1[jj]);   // s_hh
                    dp2[n * 2 + 1] = make_float2(s2[jj], s3[jj]);   // s_ht
                } else {
                    sp2[n * 2 + 1] = make_float2(s0[jj], s1[jj]);   // s_th
                    dp2[n * 2 + 0] = make_float2(s2[jj], s3[jj]);   // s_tt
                }
            }
        }
    }
}

__device__ __forceinline__ float eexp(float x) {
    x = x > 0.f ? x : 0.01f * x;
    x = fminf(x, 50.f);
    return __expf(x);
}

// Per edge (contiguous 3125-edge range per block, 1024 thr = 16 waves/CU):
// 4 exp scores -> LDS segment sums + (rel,sbin) histograms -> global totals
// (atomic) AND this block's private hpb row (non-atomic). ex4 store dropped
// (round-11): k_mkrec recomputes exp from L2-hot sp/dp (saves 25.6 MB
// round-trip; mkrec VALUBusy was 0.7%).
__global__ __launch_bounds__(1024) void k_edge(const int* __restrict__ src, const int* __restrict__ dst,
                                               const int* __restrict__ rel,
                                               const float4* __restrict__ sp, const float4* __restrict__ dp,
                                               float* __restrict__ sums,
                                               unsigned* __restrict__ histH, unsigned* __restrict__ histT,
                                               unsigned* __restrict__ hpbH, unsigned* __restrict__ hpbT) {
    __shared__ float ls[NR * 4];
    __shared__ unsigned lhH[NBK], lhT[NBK];
    int t = threadIdx.x;
    for (int i = t; i < NR * 4; i += 1024) ls[i] = 0.f;
    for (int i = t; i < NBK; i += 1024) { lhH[i] = 0u; lhT[i] = 0u; }
    __syncthreads();
    unsigned lo = blockIdx.x * EPB, hi = lo + EPB;
    for (unsigned e = lo + t; e < hi; e += 1024) {
        int s = clampi(src[e], NN), d = clampi(dst[e], NN), r = clampi(rel[e], NR);
        float4 a = sp[s], b = dp[d];
        float4 ex;
        ex.x = eexp(a.x + b.x); ex.y = eexp(a.y + b.y);
        ex.z = eexp(a.z + b.z); ex.w = eexp(a.w + b.w);
        atomicAdd(&ls[r*4+0], ex.x);
        atomicAdd(&ls[r*4+1], ex.y);
        atomicAdd(&ls[r*4+2], ex.z);
        atomicAdd(&ls[r*4+3], ex.w);
        atomicAdd(&lhH[r * NSB + s / SBW], 1u);
        atomicAdd(&lhT[r * NSB + d / SBW], 1u);
    }
    __syncthreads();
    for (int i = t; i < NR * 4; i += 1024)
        if (ls[i] != 0.f) atomicAdd(&sums[i], ls[i]);
    size_t row = (size_t)blockIdx.x * NBK;
    for (int i = t; i < NBK; i += 1024) {
        unsigned cH = lhH[i], cT = lhT[i];
        hpbH[row + i] = cH;
        hpbT[row + i] = cT;
        if (cH) atomicAdd(&histH[i], cH);
        if (cT) atomicAdd(&histT[i], cT);
    }
}

// Scan both 4000-bin total histograms -> bucket bases; invs = 1/(sums+eps).
// Wave-level shfl_up scan (2 barriers/pass vs 20 Hillis-Steele).
__global__ __launch_bounds__(1024) void k_scan2(const unsigned* __restrict__ histH,
                                                const unsigned* __restrict__ histT,
                                                const float* __restrict__ sums,
                                                unsigned* __restrict__ baseH, unsigned* __restrict__ baseT,
                                                float* __restrict__ invs) {
    __shared__ unsigned wsum[16];
    int t = threadIdx.x, lane = t & 63, wv = t >> 6;
    for (int pass = 0; pass < 2; ++pass) {
        const unsigned* h = pass ? histT : histH;
        unsigned* base = pass ? baseT : baseH;
        int j0 = t * 4;
        unsigned v[4], s = 0;
        #pragma unroll
        for (int k = 0; k < 4; ++k) { v[k] = (j0 + k < NBK) ? h[j0 + k] : 0u; s += v[k]; }
        unsigned inc = s;                       // inclusive wave scan
        #pragma unroll
        for (int d = 1; d < 64; d <<= 1) {
            unsigned u = __shfl_up(inc, d);
            if (lane >= d) inc += u;
        }
        if (lane == 63) wsum[wv] = inc;
        __syncthreads();
        unsigned wbase = 0;
        for (int i = 0; i < wv; ++i) wbase += wsum[i];
        unsigned run = wbase + inc - s;         // exclusive prefix
        #pragma unroll
        for (int k = 0; k < 4; ++k) {
            if (j0 + k < NBK) { base[j0 + k] = run; run += v[k]; }
        }
        if (t == 1023) base[NBK] = wbase + inc;
        __syncthreads();                        // wsum reuse next pass
    }
    for (int i = t; i < NR * 4; i += 1024) invs[i] = 1.f / (sums[i] + 1e-16f);
}

// Column scan, coalesced (round-11): 16 bins per block. Thread t reads its
// row's 16 contiguous bins (4 x uint4 = one full 64B line — round-10 pmc
// showed the 1-bin/block version touched 64B per 4 useful bytes: 100 MB of
// line traffic on an 8 MB array). 16 parallel wave shfl_up scans in
// registers, one barrier, coalesced write-back of exclusive prefixes+base.
__global__ __launch_bounds__(NBE) void k_colscan(unsigned* __restrict__ hpbH, unsigned* __restrict__ hpbT,
                                                 const unsigned* __restrict__ baseH,
                                                 const unsigned* __restrict__ baseT) {
    __shared__ unsigned wsum[4][CSB];
    int b = blockIdx.x;              // [0, 2*NBK/CSB)
    int pass = b >= (NBK / CSB);
    int bin0 = (pass ? b - NBK / CSB : b) * CSB;
    unsigned* h = pass ? hpbT : hpbH;
    const unsigned* base = (pass ? baseT : baseH) + bin0;
    int t = threadIdx.x, lane = t & 63, wv = t >> 6;

    unsigned v[CSB], inc[CSB];
    uint4* hp = (uint4*)(h + (size_t)t * NBK + bin0);
    #pragma unroll
    for (int q = 0; q < CSB / 4; ++q) {
        uint4 u = hp[q];
        v[q*4+0] = u.x; v[q*4+1] = u.y; v[q*4+2] = u.z; v[q*4+3] = u.w;
    }
    #pragma unroll
    for (int k = 0; k < CSB; ++k) inc[k] = v[k];
    #pragma unroll
    for (int d = 1; d < 64; d <<= 1) {
        #pragma unroll
        for (int k = 0; k < CSB; ++k) {
            unsigned u = __shfl_up(inc[k], d);
            if (lane >= d) inc[k] += u;
        }
    }
    if (lane == 63) {
        #pragma unroll
        for (int k = 0; k < CSB; ++k) wsum[wv][k] = inc[k];
    }
    __syncthreads();
    #pragma unroll
    for (int k = 0; k < CSB; ++k) {
        unsigned wbase = 0;
        for (int i = 0; i < wv; ++i) wbase += wsum[i][k];
        v[k] = base[k] + wbase + inc[k] - v[k];   // final offset, reuse v
    }
    #pragma unroll
    for (int q = 0; q < CSB / 4; ++q)
        hp[q] = make_uint4(v[q*4+0], v[q*4+1], v[q*4+2], v[q*4+3]);
}

// Single-pass scatter (1024 thr): recompute exp from L2-hot sp/dp (ex4
// stream dropped — round 11); LDS cursors from precomputed per-block
// offsets (per-block windows keep record writes run-local; round-9 showed
// global atomic cursors cost 7x write amplification).
__global__ __launch_bounds__(1024) void k_mkrec(const int* __restrict__ src, const int* __restrict__ dst,
                                                const int* __restrict__ rel,
                                                const float4* __restrict__ sp, const float4* __restrict__ dp,
                                                const float4* __restrict__ invs4,
                                                const unsigned* __restrict__ hpbH, const unsigned* __restrict__ hpbT,
                                                uint2* __restrict__ recH, uint2* __restrict__ recT) {
    __shared__ unsigned lcH[NBK], lcT[NBK];
    int t = threadIdx.x;
    size_t row = (size_t)blockIdx.x * NBK;
    for (int i = t; i < NBK; i += 1024) { lcH[i] = hpbH[row + i]; lcT[i] = hpbT[row + i]; }
    __syncthreads();
    unsigned lo = blockIdx.x * EPB, hi = lo + EPB;
    for (unsigned e = lo + t; e < hi; e += 1024) {
        int s = clampi(src[e], NN), d = clampi(dst[e], NN), r = clampi(rel[e], NR);
        float4 a = sp[s], b = dp[d];
        float4 iv = invs4[r];
        float exx = eexp(a.x + b.x), exy = eexp(a.y + b.y);
        float exz = eexp(a.z + b.z), exw = eexp(a.w + b.w);
        float w1 = exx * iv.x + exy * iv.y;
        float w2 = exz * iv.z + exw * iv.w;
        unsigned pH = atomicAdd(&lcH[r * NSB + s / SBW], 1u);
        unsigned pT = atomicAdd(&lcT[r * NSB + d / SBW], 1u);
        if (pH < NE) recH[pH] = make_uint2((unsigned)s, __float_as_uint(w1));
        if (pT < NE) recT[pT] = make_uint2((unsigned)d, __float_as_uint(w2));
    }
}

// One block per (rel,sbin) bucket. Chunked rec staging (256/LDS burst), then
// 16-lane-group gather: each wave processes 4 records/iter, 8 cols/lane via
// one b128 load — ~6 wave-instr/record vs 13 for the old 64-lane/u32 shape
// (round-7 pmc: VALUBusy 75%, MfmaUtil 0 -> VALU-issue-bound). Group reduce:
// shfl_xor(16,32) then LDS cross-wave sum.
__global__ __launch_bounds__(256) void k_accR(const uint2* __restrict__ recH, const uint2* __restrict__ recT,
                                              const unsigned* __restrict__ baseH, const unsigned* __restrict__ baseT,
                                              const __hip_bfloat16* __restrict__ xh,
                                              const __hip_bfloat16* __restrict__ xt,
                                              float* __restrict__ part) {
    __shared__ float red[3][128];
    __shared__ uint2 lrec[256];
    int b = blockIdx.x;
    int t = threadIdx.x, lane = t & 63, wv = t >> 6;
    int l16 = lane & 15, g = lane >> 4;      // col sub-slice, record subgroup
    float az[8];
    #pragma unroll
    for (int k = 0; k < 8; ++k) az[k] = 0.f;

    for (int pass = 0; pass < 2; ++pass) {
        const uint2* rec = pass ? recT : recH;
        const unsigned* base = pass ? baseT : baseH;
        const uint4* xs = (const uint4*)(pass ? xt : xh);   // row = 16 uint4
        unsigned b0 = base[b];
        unsigned cnt = base[b + 1] - b0;
        if (cnt > NE) cnt = 0;        // poison guard
        for (unsigned cb = 0; cb < cnt; cb += 256u) {
            unsigned cn = cnt - cb; if (cn > 256u) cn = 256u;
            __syncthreads();                       // prior chunk readers done
            if ((unsigned)t < cn) lrec[t] = rec[b0 + cb + t];
            __syncthreads();
            // wave wv, group g covers records j = wv*4+g, +16, ...
            for (unsigned j = (unsigned)(wv * 4 + g); j < cn; j += 16u) {
                uint2 v = lrec[j];
                unsigned nd = v.x < NN ? v.x : 0u;     // poison guard
                float w = __uint_as_float(v.y);
                uint4 u = xs[(size_t)nd * 16 + l16];
                az[0] = fmaf(w, __uint_as_float(u.x << 16),          az[0]);
                az[1] = fmaf(w, __uint_as_float(u.x & 0xffff0000u),  az[1]);
                az[2] = fmaf(w, __uint_as_float(u.y << 16),          az[2]);
                az[3] = fmaf(w, __uint_as_float(u.y & 0xffff0000u),  az[3]);
                az[4] = fmaf(w, __uint_as_float(u.z << 16),          az[4]);
                az[5] = fmaf(w, __uint_as_float(u.z & 0xffff0000u),  az[5]);
                az[6] = fmaf(w, __uint_as_float(u.w << 16),          az[6]);
                az[7] = fmaf(w, __uint_as_float(u.w & 0xffff0000u),  az[7]);
            }
        }
    }
    // reduce the 4 record-subgroups: lanes 0-15 end with column totals
    #pragma unroll
    for (int k = 0; k < 8; ++k) {
        az[k] += __shfl_xor(az[k], 16);
        az[k] += __shfl_xor(az[k], 32);
    }
    __syncthreads();                  // lrec dead; red reuse safe
    if (wv > 0 && lane < 16) {
        #pragma unroll
        for (int k = 0; k < 8; ++k) red[wv - 1][l16 * 8 + k] = az[k];
    }
    __syncthreads();
    if (wv == 0 && lane < 16) {
        #pragma unroll
        for (int k = 0; k < 8; ++k) {
            float s = az[k] + red[0][l16 * 8 + k] + red[1][l16 * 8 + k] + red[2][l16 * 8 + k];
            part[(size_t)b * KRH + l16 * 8 + k] = s;
        }
    }
}

// out[r][c] = 0.25 * sum_sbin part[r*8+sbin][c]; dtype follows input.
__global__ __launch_bounds__(256) void k_out(const float* __restrict__ part,
                                             const unsigned* __restrict__ flag, void* __restrict__ out) {
    int i = blockIdx.x * 256 + threadIdx.x;
    if (i < NR * KRH) {
        int r = i >> 7, c = i & 127;
        float v = 0.f;
        for (int s = 0; s < NSB; ++s) v += part[(size_t)(r * NSB + s) * KRH + c];
        v *= 0.25f;                   // / num_heads(2) / 2
        if (!isfinite(v)) v = 0.f;
        if (flag[0]) ((__hip_bfloat16*)out)[i] = __float2bfloat16(v);
        else         ((float*)out)[i] = v;
    }
}

extern "C" void kernel_launch(void* const* d_in, const int* in_sizes, int n_in,
                              void* d_out, int out_size, void* d_ws, size_t ws_size,
                              hipStream_t stream) {
    const void* xe  = d_in[0];
    const int* eidx = (const int*)d_in[1];
    const int* rel  = (const int*)d_in[2];
    const void* wh  = d_in[3];
    const void* wt  = d_in[4];
    const void* ahp = d_in[5];
    const void* atp = d_in[6];

    const int* src = eidx;
    const int* dst = eidx + NE;

    char* ws = (char*)d_ws;
    __hip_bfloat16* xh = (__hip_bfloat16*)(ws + OFF_XH);
    __hip_bfloat16* xt = (__hip_bfloat16*)(ws + OFF_XT);
    float4*   sp     = (float4*)(ws + OFF_SP);
    float4*   dp     = (float4*)(ws + OFF_DP);
    float*    sums   = (float*)(ws + OFF_SUMS);
    unsigned* histH  = (unsigned*)(ws + OFF_HISTH);
    unsigned* histT  = (unsigned*)(ws + OFF_HISTT);
    float*    invs   = (float*)(ws + OFF_INVS);
    unsigned* baseH  = (unsigned*)(ws + OFF_BASEH);
    unsigned* baseT  = (unsigned*)(ws + OFF_BASET);
    uint2*    recH   = (uint2*)(ws + OFF_RECH);
    uint2*    recT   = (uint2*)(ws + OFF_RECT);
    float*    partp  = (float*)(ws + OFF_PART);
    float*    ah32   = (float*)(ws + OFF_AH);
    float*    at32   = (float*)(ws + OFF_AT);
    unsigned* flag   = (unsigned*)(ws + OFF_FLAG);
    __bf16*   whh    = (__bf16*)(ws + OFF_WHH);
    __bf16*   wth    = (__bf16*)(ws + OFF_WTH);
    unsigned* hpbH   = (unsigned*)(ws + OFF_HPBH);
    unsigned* hpbT   = (unsigned*)(ws + OFF_HPBT);

    k_init<<<161, 256, 0, stream>>>((const unsigned*)xe, ahp, atp, wh, wt, flag, ah32, at32,
                                     whh, wth, (unsigned*)(ws + OFF_SUMS));
    k_gemm<<<512, 512, 0, stream>>>(xe, flag, whh, wth, ah32, at32,
                                    xh, xt, (float2*)sp, (float2*)dp);
    k_edge<<<NBE, 1024, 0, stream>>>(src, dst, rel, sp, dp, sums, histH, histT, hpbH, hpbT);
    k_scan2<<<1, 1024, 0, stream>>>(histH, histT, sums, baseH, baseT, invs);
    k_colscan<<<2 * (NBK / CSB), NBE, 0, stream>>>(hpbH, hpbT, baseH, baseT);
    k_mkrec<<<NBE, 1024, 0, stream>>>(src, dst, rel, sp, dp, (const float4*)invs, hpbH, hpbT, recH, recT);
    k_accR<<<NBK, 256, 0, stream>>>(recH, recT, baseH, baseT, xh, xt, partp);
    k_out<<<(NR * KRH + 255) / 256, 256, 0, stream>>>(partp, flag, d_out);
}